// Round 4
// baseline (1576.423 us; speedup 1.0000x reference)
//
#include <hip/hip_runtime.h>
#include <hip/hip_bf16.h>
#include <stdint.h>

#define B4 4096
#define KZ 1056   // padded z width: 1024 + 1 (ones col for bias) + 31 zero pad
#define KH 160    // padded hypernet-input width: 132 + 1 + pad

typedef short bf16x8 __attribute__((ext_vector_type(8)));
typedef float f32x4 __attribute__((ext_vector_type(4)));

__device__ __forceinline__ float b2f(uint16_t u){
  union {float f; uint32_t i;} v; v.i = ((uint32_t)u)<<16; return v.f;
}
__device__ __forceinline__ uint16_t f2b(float f){
  union {float fv; uint32_t i;} v; v.fv = f;
  uint32_t r = v.i + 0x7FFFu + ((v.i>>16)&1u);
  return (uint16_t)(r>>16);
}
__device__ __forceinline__ void gload16(const void* g, void* l){
  __builtin_amdgcn_global_load_lds(
      (__attribute__((address_space(1))) void*)(g),
      (__attribute__((address_space(3))) void*)(l), 16, 0, 0);
}

// ---------------------------------------------------------------------------
// Transpose+pack: dst[c][k] (bf16, K-contiguous) from src fp32 [Ksrc][src_ld].
// Row k==Ksrc gets bias[sc]; k>Ksrc gets 0. Column map handles din padding:
// o=c/din_dst, i=c%din_dst, valid iff i<din_src.
// ---------------------------------------------------------------------------
__global__ __launch_bounds__(256) void transpose_pack(
    const float* __restrict__ src, const float* __restrict__ bias,
    uint16_t* __restrict__ dst,
    int Ncols, int Kdst, int Ksrc, int src_ld, int din_dst, int din_src)
{
  __shared__ float tile[32][33];
  int ct = blockIdx.x, kt = blockIdx.y;
  int tid = threadIdx.x;
  int cl = tid & 31, kg = tid >> 5;
  #pragma unroll
  for (int r = 0; r < 4; ++r){
    int kl = kg*4 + r;
    int k  = kt*32 + kl;
    int c  = ct*32 + cl;
    float v = 0.f;
    if (c < Ncols){
      int o = c / din_dst, i = c - o*din_dst;
      if (i < din_src){
        int sc = o*din_src + i;
        if (k < Ksrc)       v = src[(size_t)k*src_ld + sc];
        else if (k == Ksrc) v = bias[sc];
      }
    }
    tile[kl][cl] = v;
  }
  __syncthreads();
  #pragma unroll
  for (int r = 0; r < 4; ++r){
    int cl2 = kg*4 + r;
    int c = ct*32 + cl2;
    int k = kt*32 + (tid & 31);
    if (c < Ncols) dst[(size_t)c*Kdst + k] = f2b(tile[tid & 31][cl2]);
  }
}

// hinp[b][k] bf16: [obs | prefs | 1 | 0...], width KH
__global__ __launch_bounds__(256) void pack_hin(
    const float* __restrict__ obs, const float* __restrict__ prefs,
    uint16_t* __restrict__ hinp)
{
  int idx = blockIdx.x*256 + threadIdx.x;   // over B4*KH
  int b = idx / KH, k = idx - b*KH;
  float v;
  if (k < 128)      v = obs[b*128 + k];
  else if (k < 132) v = prefs[b*4 + (k-128)];
  else              v = (k == 132) ? 1.f : 0.f;
  hinp[idx] = f2b(v);
}

// x0T[c][b] bf16 transposed: c<128 obs, c<160 action, c<164 prefs, else 0.
// 192 rows (din padded to 192).
__global__ __launch_bounds__(256) void pack_x0T(
    const float* __restrict__ obs, const float* __restrict__ act,
    const float* __restrict__ prefs, uint16_t* __restrict__ x0T)
{
  int idx = blockIdx.x*256 + threadIdx.x;   // over 192*B4
  int c = idx >> 12;
  int b = idx & (B4-1);
  float v = 0.f;
  if (c < 128)      v = obs[b*128 + c];
  else if (c < 160) v = act[b*32 + (c-128)];
  else if (c < 164) v = prefs[b*4 + (c-160)];
  x0T[idx] = f2b(v);
}

// set cols 1024..1055 of z1p and zp: 1.0 at 1024, zeros after
__global__ __launch_bounds__(256) void zinit(uint16_t* __restrict__ z1p,
                                             uint16_t* __restrict__ zp)
{
  int idx = blockIdx.x*256 + threadIdx.x;   // over B4*64
  int t = idx & 63;
  int row = idx >> 6;
  uint16_t* p = (t < 32) ? z1p : zp;
  int col = 1024 + (t & 31);
  p[(size_t)row*KZ + col] = ((t & 31) == 0) ? (uint16_t)0x3F80 : (uint16_t)0;
}

// ---------------------------------------------------------------------------
// Generic 128x128 MFMA GEMM: C[M,N] = act(A[M,K] @ BT[N,K]^T)
// A, BT bf16 (K-contiguous rows), C fp32 or bf16. 4 waves, wave = 32-row slab.
// TRANS=1: store fp32 transposed C^T[col*ldc + row] (for bias/scale buffers).
// ---------------------------------------------------------------------------
template<int RELU, int OUTBF, int TRANS>
__global__ __launch_bounds__(256) void gemm128(
    const uint16_t* __restrict__ A, int lda,
    const uint16_t* __restrict__ BT, int ldb,
    void* __restrict__ Cv, int ldc, int K)
{
  __shared__ char smA[128*64];
  __shared__ char smB[128*64];
  int tid = threadIdx.x, w = tid >> 6, lane = tid & 63;
  int m0 = blockIdx.x*128, n0 = blockIdx.y*128;
  const uint16_t* Ab = A  + (size_t)m0*lda;
  const uint16_t* Bb = BT + (size_t)n0*ldb;
  f32x4 acc[2][8];
  #pragma unroll
  for (int mf = 0; mf < 2; ++mf)
    #pragma unroll
    for (int nf = 0; nf < 8; ++nf) acc[mf][nf] = (f32x4){0.f,0.f,0.f,0.f};
  int colg = lane & 15, hi = lane >> 4;

  for (int k0 = 0; k0 < K; k0 += 32){
    #pragma unroll
    for (int p = 0; p < 2; ++p){
      int rb = p*4 + w;
      int row = rb*16 + (lane >> 2);
      int chunk = (lane & 3) ^ ((row >> 1) & 3);
      gload16(Ab + (size_t)row*lda + k0 + chunk*8, &smA[rb*1024]);
      gload16(Bb + (size_t)row*ldb + k0 + chunk*8, &smB[rb*1024]);
    }
    __syncthreads();
    bf16x8 af[2];
    #pragma unroll
    for (int mf = 0; mf < 2; ++mf){
      int row = w*32 + mf*16 + colg;
      af[mf] = *(const bf16x8*)&smA[row*64 + ((hi ^ ((row>>1)&3)) << 4)];
    }
    #pragma unroll
    for (int nf = 0; nf < 8; ++nf){
      int row = nf*16 + colg;
      bf16x8 bfr = *(const bf16x8*)&smB[row*64 + ((hi ^ ((row>>1)&3)) << 4)];
      acc[0][nf] = __builtin_amdgcn_mfma_f32_16x16x32_bf16(af[0], bfr, acc[0][nf], 0,0,0);
      acc[1][nf] = __builtin_amdgcn_mfma_f32_16x16x32_bf16(af[1], bfr, acc[1][nf], 0,0,0);
    }
    __syncthreads();
  }
  #pragma unroll
  for (int mf = 0; mf < 2; ++mf){
    #pragma unroll
    for (int nf = 0; nf < 8; ++nf){
      int col = n0 + nf*16 + colg;
      #pragma unroll
      for (int r = 0; r < 4; ++r){
        int row = m0 + w*32 + mf*16 + hi*4 + r;
        float v = acc[mf][nf][r];
        if (RELU) v = v > 0.f ? v : 0.f;
        if (TRANS)      ((float*)Cv)[(size_t)col*ldc + row] = v;
        else if (OUTBF) ((uint16_t*)Cv)[(size_t)row*ldc + col] = f2b(v);
        else            ((float*)Cv)[(size_t)row*ldc + col] = v;
      }
    }
  }
}

// ---------------------------------------------------------------------------
// Fused hypernet layer, v4: A (z) fragments go global->VGPR directly
// (z is L2-hot; per-lane frag = 16 contiguous bytes), LDS holds only B
// (weights, reused x4 across wm waves), double-buffered, prefetch one step
// ahead with counted vmcnt. 8 waves = 4M x 2N, wave tile 64 x DINP/2.
// Small LDS (24KB max) + launch_bounds(512,4) => 2+ blocks/CU co-resident.
// Epilogue: per-lane dot with xT, colg shuffle-reduce, cross-wn LDS reduce,
// bias+scale (+relu), store transposed outT[o][b].
// ---------------------------------------------------------------------------
template<int DINP>
__global__ __launch_bounds__(512, 4) void hyper_layer(
    const uint16_t* __restrict__ zp,     // [B4, KZ]
    const uint16_t* __restrict__ WpT,    // [128*DINP, KZ]
    const uint16_t* __restrict__ xT,     // [DINP, B4]
    const float*  __restrict__ bsbT,     // [256, B4] transposed: o=b, 128+o=s
    uint16_t* __restrict__ outT,         // [128, B4]
    int relu)
{
  constexpr int NFW   = DINP/32;        // B frags per wave (wave N-tile DINP/2)
  constexpr int NW    = DINP/2;
  constexpr int NG    = DINP/16;        // 1KB B staging groups per k-step
  constexpr int BUFSZ = DINP*64;        // one B buffer
  constexpr int NT    = KZ/32;          // 33 k-steps
  __shared__ char sm[2*BUFSZ];

  int tid = threadIdx.x, w = tid >> 6, lane = tid & 63;
  int wm = w >> 1, wn = w & 1;
  // XCD-aware decode: each XCD owns 2 m-tiles x all 128 neurons
  int f = blockIdx.x;
  int xcd = f & 7;
  int j = f >> 3;
  int o = j >> 1;
  int mt = xcd*2 + (j & 1);
  int m0 = mt*256;
  const uint16_t* Ab = zp  + (size_t)m0*KZ;
  const uint16_t* Bb = WpT + (size_t)o*DINP*KZ;
  int colg = lane & 15, hi = lane >> 4;
  int lrow = lane >> 2, lch = lane & 3;

  f32x4 acc[4][NFW];
  #pragma unroll
  for (int mf = 0; mf < 4; ++mf)
    #pragma unroll
    for (int nf = 0; nf < NFW; ++nf) acc[mf][nf] = (f32x4){0.f,0.f,0.f,0.f};

  // per-wave B staging: wave w stages group w; waves < NG-8 also group w+8
  auto STAGEB = [&](int t, char* base){
    int k0 = t*32;
    { int row = w*16 + lrow;
      int chunk = lch ^ ((row >> 1) & 3);
      gload16(Bb + (size_t)row*KZ + k0 + chunk*8, base + w*1024); }
    if constexpr (NG > 8){
      if (w < NG-8){
        int g = w + 8;
        int row = g*16 + lrow;
        int chunk = lch ^ ((row >> 1) & 3);
        gload16(Bb + (size_t)row*KZ + k0 + chunk*8, base + g*1024);
      }
    }
  };
  auto LOADA = [&](int t, bf16x8* R){
    int k0 = t*32;
    #pragma unroll
    for (int mf = 0; mf < 4; ++mf){
      int row = wm*64 + mf*16 + colg;
      R[mf] = *(const bf16x8*)(Ab + (size_t)row*KZ + k0 + hi*8);
    }
  };
  auto WAITB = [&](){
    // wait for previous step's A-loads(4) + B-stages(G): exactly the newest
    // 4+G ops (this step's prefetch) may remain outstanding. FIFO retirement
    // guarantees the older batch is complete.
    if constexpr (NG > 8){
      if (w < NG-8) asm volatile("s_waitcnt vmcnt(6)" ::: "memory");
      else          asm volatile("s_waitcnt vmcnt(5)" ::: "memory");
    } else {
      asm volatile("s_waitcnt vmcnt(5)" ::: "memory");
    }
  };
  auto COMPUTE = [&](const bf16x8* R, const char* base){
    #pragma unroll
    for (int nf = 0; nf < NFW; ++nf){
      int c = wn*NW + nf*16 + colg;
      bf16x8 bfr = *(const bf16x8*)(base + c*64 + ((hi ^ ((c>>1)&3)) << 4));
      #pragma unroll
      for (int mf = 0; mf < 4; ++mf)
        acc[mf][nf] = __builtin_amdgcn_mfma_f32_16x16x32_bf16(R[mf], bfr, acc[mf][nf], 0,0,0);
    }
  };

  bf16x8 Ra[4], Rb[4];
  LOADA(0, Ra);
  STAGEB(0, sm);
  // 16 pairs of steps (t = 0..31), tail t = 32
  for (int tt = 0; tt < (NT-1)/2; ++tt){
    int t = tt*2;
    // even step: prefetch t+1, compute t from Ra / buf0
    LOADA(t+1, Rb);
    STAGEB(t+1, sm + BUFSZ);
    WAITB();
    __builtin_amdgcn_s_barrier();
    COMPUTE(Ra, sm);
    asm volatile("s_waitcnt lgkmcnt(0)" ::: "memory");
    __builtin_amdgcn_s_barrier();
    // odd step: prefetch t+2, compute t+1 from Rb / buf1
    LOADA(t+2, Ra);
    STAGEB(t+2, sm);
    WAITB();
    __builtin_amdgcn_s_barrier();
    COMPUTE(Rb, sm + BUFSZ);
    asm volatile("s_waitcnt lgkmcnt(0)" ::: "memory");
    __builtin_amdgcn_s_barrier();
  }
  // tail step t = NT-1 = 32 (even; A in Ra, B in buf0)
  asm volatile("s_waitcnt vmcnt(0)" ::: "memory");
  __builtin_amdgcn_s_barrier();
  COMPUTE(Ra, sm);

  // ---- epilogue: contract W rows with x ----
  float pp[4][4];
  #pragma unroll
  for (int mf = 0; mf < 4; ++mf)
    #pragma unroll
    for (int r = 0; r < 4; ++r) pp[mf][r] = 0.f;

  #pragma unroll
  for (int nf = 0; nf < NFW; ++nf){
    int c = wn*NW + nf*16 + colg;
    #pragma unroll
    for (int mf = 0; mf < 4; ++mf){
      int b0 = m0 + wm*64 + mf*16 + hi*4;
      ushort4 xv = *(const ushort4*)(xT + (size_t)c*B4 + b0);
      f32x4 a = acc[mf][nf];
      pp[mf][0] += a[0]*b2f(xv.x); pp[mf][1] += a[1]*b2f(xv.y);
      pp[mf][2] += a[2]*b2f(xv.z); pp[mf][3] += a[3]*b2f(xv.w);
    }
  }
  #pragma unroll
  for (int mf = 0; mf < 4; ++mf)
    #pragma unroll
    for (int off = 1; off < 16; off <<= 1){
      pp[mf][0] += __shfl_xor(pp[mf][0], off);
      pp[mf][1] += __shfl_xor(pp[mf][1], off);
      pp[mf][2] += __shfl_xor(pp[mf][2], off);
      pp[mf][3] += __shfl_xor(pp[mf][3], off);
    }

  // cross-wn reduction via LDS (reuse sm; sync first: compute reads done)
  __syncthreads();
  float* red = (float*)sm;    // [2][256]
  if (colg == 0){
    #pragma unroll
    for (int mf = 0; mf < 4; ++mf){
      int rloc = wm*64 + mf*16 + hi*4;
      #pragma unroll
      for (int r = 0; r < 4; ++r) red[wn*256 + rloc + r] = pp[mf][r];
    }
  }
  __syncthreads();
  if (wn == 0 && colg == 0){
    #pragma unroll
    for (int mf = 0; mf < 4; ++mf){
      int rloc = wm*64 + mf*16 + hi*4;
      int b0 = m0 + rloc;
      float4 bv = *(const float4*)(bsbT + (size_t)o*B4 + b0);
      float4 sv = *(const float4*)(bsbT + (size_t)(128+o)*B4 + b0);
      float bb[4] = {bv.x, bv.y, bv.z, bv.w};
      float ss[4] = {sv.x, sv.y, sv.z, sv.w};
      ushort4 st;
      uint16_t* sp = (uint16_t*)&st;
      #pragma unroll
      for (int r = 0; r < 4; ++r){
        float val = (pp[mf][r] + red[256 + rloc + r] + bb[r]) * ss[r];
        if (relu) val = val > 0.f ? val : 0.f;
        sp[r] = f2b(val);
      }
      *(ushort4*)(outT + (size_t)o*B4 + b0) = st;
    }
  }
}

// final layer: out[b,o] = (sum_i w2[b,o*128+i]*x2[i,b] + b2[b,o]) * s2[b,o]
__global__ __launch_bounds__(256) void finalize_k(
    const float* __restrict__ w2, const uint16_t* __restrict__ x2T,
    const float* __restrict__ bs2, float* __restrict__ out)
{
  int tid = threadIdx.x;
  int o = tid & 3;
  int b = blockIdx.x*64 + (tid >> 2);
  const float* wr = w2 + (size_t)b*512 + o*128;
  float dot = 0.f;
  #pragma unroll
  for (int i = 0; i < 128; i += 4){
    float4 wv = *(const float4*)(wr + i);
    dot += wv.x * b2f(x2T[(size_t)(i+0)*B4 + b]);
    dot += wv.y * b2f(x2T[(size_t)(i+1)*B4 + b]);
    dot += wv.z * b2f(x2T[(size_t)(i+2)*B4 + b]);
    dot += wv.w * b2f(x2T[(size_t)(i+3)*B4 + b]);
  }
  float bv = bs2[(size_t)b*128 + o];
  float sv = bs2[(size_t)b*128 + 4 + o];
  out[b*4 + o] = (dot + bv) * sv;
}

// ---------------------------------------------------------------------------
extern "C" void kernel_launch(void* const* d_in, const int* in_sizes, int n_in,
                              void* d_out, int out_size, void* d_ws, size_t ws_size,
                              hipStream_t stream)
{
  const float* obs   = (const float*)d_in[0];
  const float* act   = (const float*)d_in[1];
  const float* prefs = (const float*)d_in[2];
  const float* We1 = (const float*)d_in[3];
  const float* be1 = (const float*)d_in[4];
  const float* We2 = (const float*)d_in[5];
  const float* be2 = (const float*)d_in[6];
  const float* Ww0 = (const float*)d_in[7],  *bw0 = (const float*)d_in[8];
  const float* Wb0 = (const float*)d_in[9],  *bb0 = (const float*)d_in[10];
  const float* Ws0 = (const float*)d_in[11], *bs0i = (const float*)d_in[12];
  const float* Ww1 = (const float*)d_in[13], *bw1 = (const float*)d_in[14];
  const float* Wb1 = (const float*)d_in[15], *bb1 = (const float*)d_in[16];
  const float* Ws1 = (const float*)d_in[17], *bs1i = (const float*)d_in[18];
  const float* Ww2 = (const float*)d_in[19], *bw2 = (const float*)d_in[20];
  const float* Wb2 = (const float*)d_in[21], *bb2 = (const float*)d_in[22];
  const float* Ws2 = (const float*)d_in[23], *bs2i = (const float*)d_in[24];

  char* ws = (char*)d_ws;
  size_t off = 0;
  auto alloc = [&](size_t bytes)->char*{
    char* p = ws + off; off += (bytes + 255) & ~(size_t)255; return p;
  };
  uint16_t* WpT0  = (uint16_t*)alloc((size_t)24576*KZ*2);  // 128 * 192 rows
  uint16_t* WpT1  = (uint16_t*)alloc((size_t)16384*KZ*2);
  uint16_t* WpT2  = (uint16_t*)alloc((size_t)512*KZ*2);
  uint16_t* We1T  = (uint16_t*)alloc((size_t)1024*KH*2);
  uint16_t* We2T  = (uint16_t*)alloc((size_t)1024*KZ*2);
  uint16_t* Wbs0T = (uint16_t*)alloc((size_t)256*KZ*2);
  uint16_t* Wbs1T = (uint16_t*)alloc((size_t)256*KZ*2);
  uint16_t* Wbs2T = (uint16_t*)alloc((size_t)128*KZ*2);
  uint16_t* hinp  = (uint16_t*)alloc((size_t)B4*KH*2);
  uint16_t* z1p   = (uint16_t*)alloc((size_t)B4*KZ*2);
  uint16_t* zp    = (uint16_t*)alloc((size_t)B4*KZ*2);
  float*    bsb0  = (float*)alloc((size_t)256*B4*4);   // transposed [256][B4]
  float*    bsb1  = (float*)alloc((size_t)256*B4*4);   // transposed [256][B4]
  float*    bsb2  = (float*)alloc((size_t)B4*128*4);
  uint16_t* x0T   = (uint16_t*)alloc((size_t)192*B4*2);
  uint16_t* x1T   = (uint16_t*)alloc((size_t)128*B4*2);
  uint16_t* x2T   = (uint16_t*)alloc((size_t)128*B4*2);
  float*    w2    = (float*)alloc((size_t)B4*512*4);
  (void)ws_size; (void)in_sizes; (void)n_in; (void)out_size;

  hipMemsetAsync(Wbs2T, 0, (size_t)128*KZ*2, stream);

  dim3 blk(256);
  auto tg = [](int nc, int kd){ return dim3((nc+31)/32, kd/32); };
  transpose_pack<<<tg(24576,KZ),blk,0,stream>>>(Ww0, bw0, WpT0, 24576, KZ, 1024, 20992, 192, 164);
  transpose_pack<<<tg(16384,KZ),blk,0,stream>>>(Ww1, bw1, WpT1, 16384, KZ, 1024, 16384, 128, 128);
  transpose_pack<<<tg(512,KZ),blk,0,stream>>>(Ww2, bw2, WpT2, 512, KZ, 1024, 512, 128, 128);
  transpose_pack<<<tg(1024,KH),blk,0,stream>>>(We1, be1, We1T, 1024, KH, 132, 1024, 1024, 1024);
  transpose_pack<<<tg(1024,KZ),blk,0,stream>>>(We2, be2, We2T, 1024, KZ, 1024, 1024, 1024, 1024);
  transpose_pack<<<tg(128,KZ),blk,0,stream>>>(Wb0, bb0, Wbs0T,          128, KZ, 1024, 128, 128, 128);
  transpose_pack<<<tg(128,KZ),blk,0,stream>>>(Ws0, bs0i, Wbs0T + 128*KZ,128, KZ, 1024, 128, 128, 128);
  transpose_pack<<<tg(128,KZ),blk,0,stream>>>(Wb1, bb1, Wbs1T,          128, KZ, 1024, 128, 128, 128);
  transpose_pack<<<tg(128,KZ),blk,0,stream>>>(Ws1, bs1i, Wbs1T + 128*KZ,128, KZ, 1024, 128, 128, 128);
  transpose_pack<<<tg(4,KZ),blk,0,stream>>>(Wb2, bb2, Wbs2T,        4, KZ, 1024, 4, 4, 4);
  transpose_pack<<<tg(4,KZ),blk,0,stream>>>(Ws2, bs2i, Wbs2T + 4*KZ,4, KZ, 1024, 4, 4, 4);

  pack_hin<<<dim3(B4*KH/256),blk,0,stream>>>(obs, prefs, hinp);
  pack_x0T<<<dim3(192*B4/256),blk,0,stream>>>(obs, act, prefs, x0T);
  zinit<<<dim3(B4*64/256),blk,0,stream>>>(z1p, zp);

  // z1 = relu(hin' @ We1')   [B,1024] bf16 into z1p (stride KZ)
  gemm128<1,1,0><<<dim3(32,8),blk,0,stream>>>(hinp, KH, We1T, KH, z1p, KZ, KH);
  // z = relu(z1' @ We2')     [B,1024] bf16 into zp (stride KZ)
  gemm128<1,1,0><<<dim3(32,8),blk,0,stream>>>(z1p, KZ, We2T, KZ, zp, KZ, KZ);
  // per-layer bias/scale heads, fp32 TRANSPOSED [256][B4]: row o=b, 128+o=s
  gemm128<0,0,1><<<dim3(32,2),blk,0,stream>>>(zp, KZ, Wbs0T, KZ, bsb0, B4, KZ);
  gemm128<0,0,1><<<dim3(32,2),blk,0,stream>>>(zp, KZ, Wbs1T, KZ, bsb1, B4, KZ);
  gemm128<0,0,0><<<dim3(32,1),blk,0,stream>>>(zp, KZ, Wbs2T, KZ, bsb2, 128, KZ);

  // fused hyper layers 0 and 1 (XCD-swizzled 1D grid: 8 xcd * 128 o * 2 m)
  hyper_layer<192><<<dim3(2048),dim3(512),0,stream>>>(zp, WpT0, x0T, bsb0, x1T, 1);
  hyper_layer<128><<<dim3(2048),dim3(512),0,stream>>>(zp, WpT1, x1T, bsb1, x2T, 1);

  // layer 2: materialize small w2 then finalize
  gemm128<0,0,0><<<dim3(32,4),blk,0,stream>>>(zp, KZ, WpT2, KZ, w2, 512, KZ);
  finalize_k<<<dim3(B4/64),blk,0,stream>>>(w2, x2T, bsb2, (float*)d_out);
}

// Round 5
// 662.834 us; speedup vs baseline: 2.3783x; 2.3783x over previous
//
#include <hip/hip_runtime.h>
#include <hip/hip_bf16.h>
#include <stdint.h>

#define B4 4096
#define KZ 1088   // padded z width: 1024 + 1 (ones col for bias) + 63 zero pad (17 x 64)
#define KH 160    // padded hypernet-input width: 132 + 1 + pad

typedef short bf16x8 __attribute__((ext_vector_type(8)));
typedef float f32x4 __attribute__((ext_vector_type(4)));

__device__ __forceinline__ float b2f(uint16_t u){
  union {float f; uint32_t i;} v; v.i = ((uint32_t)u)<<16; return v.f;
}
__device__ __forceinline__ uint16_t f2b(float f){
  union {float fv; uint32_t i;} v; v.fv = f;
  uint32_t r = v.i + 0x7FFFu + ((v.i>>16)&1u);
  return (uint16_t)(r>>16);
}
__device__ __forceinline__ void gload16(const void* g, void* l){
  __builtin_amdgcn_global_load_lds(
      (__attribute__((address_space(1))) void*)(g),
      (__attribute__((address_space(3))) void*)(l), 16, 0, 0);
}

// ---------------------------------------------------------------------------
// Transpose+pack: dst[c][k] (bf16, K-contiguous) from src fp32 [Ksrc][src_ld].
// Row k==Ksrc gets bias[sc]; k>Ksrc gets 0. Column map handles din padding:
// o=c/din_dst, i=c%din_dst, valid iff i<din_src.
// ---------------------------------------------------------------------------
__global__ __launch_bounds__(256) void transpose_pack(
    const float* __restrict__ src, const float* __restrict__ bias,
    uint16_t* __restrict__ dst,
    int Ncols, int Kdst, int Ksrc, int src_ld, int din_dst, int din_src)
{
  __shared__ float tile[32][33];
  int ct = blockIdx.x, kt = blockIdx.y;
  int tid = threadIdx.x;
  int cl = tid & 31, kg = tid >> 5;
  #pragma unroll
  for (int r = 0; r < 4; ++r){
    int kl = kg*4 + r;
    int k  = kt*32 + kl;
    int c  = ct*32 + cl;
    float v = 0.f;
    if (c < Ncols){
      int o = c / din_dst, i = c - o*din_dst;
      if (i < din_src){
        int sc = o*din_src + i;
        if (k < Ksrc)       v = src[(size_t)k*src_ld + sc];
        else if (k == Ksrc) v = bias[sc];
      }
    }
    tile[kl][cl] = v;
  }
  __syncthreads();
  #pragma unroll
  for (int r = 0; r < 4; ++r){
    int cl2 = kg*4 + r;
    int c = ct*32 + cl2;
    int k = kt*32 + (tid & 31);
    if (c < Ncols) dst[(size_t)c*Kdst + k] = f2b(tile[tid & 31][cl2]);
  }
}

// hinp[b][k] bf16: [obs | prefs | 1 | 0...], width KH
__global__ __launch_bounds__(256) void pack_hin(
    const float* __restrict__ obs, const float* __restrict__ prefs,
    uint16_t* __restrict__ hinp)
{
  int idx = blockIdx.x*256 + threadIdx.x;   // over B4*KH
  int b = idx / KH, k = idx - b*KH;
  float v;
  if (k < 128)      v = obs[b*128 + k];
  else if (k < 132) v = prefs[b*4 + (k-128)];
  else              v = (k == 132) ? 1.f : 0.f;
  hinp[idx] = f2b(v);
}

// x0T[c][b] bf16 transposed: c<128 obs, c<160 action, c<164 prefs, else 0.
// 192 rows (din padded to 192).
__global__ __launch_bounds__(256) void pack_x0T(
    const float* __restrict__ obs, const float* __restrict__ act,
    const float* __restrict__ prefs, uint16_t* __restrict__ x0T)
{
  int idx = blockIdx.x*256 + threadIdx.x;   // over 192*B4
  int c = idx >> 12;
  int b = idx & (B4-1);
  float v = 0.f;
  if (c < 128)      v = obs[b*128 + c];
  else if (c < 160) v = act[b*32 + (c-128)];
  else if (c < 164) v = prefs[b*4 + (c-160)];
  x0T[idx] = f2b(v);
}

// set cols 1024..1087 of z1p and zp: 1.0 at 1024, zeros after
__global__ __launch_bounds__(256) void zinit(uint16_t* __restrict__ z1p,
                                             uint16_t* __restrict__ zp)
{
  int idx = blockIdx.x*256 + threadIdx.x;   // over B4*128
  int t = idx & 127;
  int row = idx >> 7;
  uint16_t* p = (t < 64) ? z1p : zp;
  int col = 1024 + (t & 63);
  p[(size_t)row*KZ + col] = ((t & 63) == 0) ? (uint16_t)0x3F80 : (uint16_t)0;
}

// ---------------------------------------------------------------------------
// Generic 128x128 MFMA GEMM: C[M,N] = act(A[M,K] @ BT[N,K]^T)
// A, BT bf16 (K-contiguous rows), C fp32 or bf16. 4 waves, wave = 32-row slab.
// TRANS=1: store fp32 transposed C^T[col*ldc + row] (for bias/scale buffers).
// ---------------------------------------------------------------------------
template<int RELU, int OUTBF, int TRANS>
__global__ __launch_bounds__(256) void gemm128(
    const uint16_t* __restrict__ A, int lda,
    const uint16_t* __restrict__ BT, int ldb,
    void* __restrict__ Cv, int ldc, int K)
{
  __shared__ char smA[128*64];
  __shared__ char smB[128*64];
  int tid = threadIdx.x, w = tid >> 6, lane = tid & 63;
  int m0 = blockIdx.x*128, n0 = blockIdx.y*128;
  const uint16_t* Ab = A  + (size_t)m0*lda;
  const uint16_t* Bb = BT + (size_t)n0*ldb;
  f32x4 acc[2][8];
  #pragma unroll
  for (int mf = 0; mf < 2; ++mf)
    #pragma unroll
    for (int nf = 0; nf < 8; ++nf) acc[mf][nf] = (f32x4){0.f,0.f,0.f,0.f};
  int colg = lane & 15, hi = lane >> 4;

  for (int k0 = 0; k0 < K; k0 += 32){
    #pragma unroll
    for (int p = 0; p < 2; ++p){
      int rb = p*4 + w;
      int row = rb*16 + (lane >> 2);
      int chunk = (lane & 3) ^ ((row >> 1) & 3);
      gload16(Ab + (size_t)row*lda + k0 + chunk*8, &smA[rb*1024]);
      gload16(Bb + (size_t)row*ldb + k0 + chunk*8, &smB[rb*1024]);
    }
    __syncthreads();
    bf16x8 af[2];
    #pragma unroll
    for (int mf = 0; mf < 2; ++mf){
      int row = w*32 + mf*16 + colg;
      af[mf] = *(const bf16x8*)&smA[row*64 + ((hi ^ ((row>>1)&3)) << 4)];
    }
    #pragma unroll
    for (int nf = 0; nf < 8; ++nf){
      int row = nf*16 + colg;
      bf16x8 bfr = *(const bf16x8*)&smB[row*64 + ((hi ^ ((row>>1)&3)) << 4)];
      acc[0][nf] = __builtin_amdgcn_mfma_f32_16x16x32_bf16(af[0], bfr, acc[0][nf], 0,0,0);
      acc[1][nf] = __builtin_amdgcn_mfma_f32_16x16x32_bf16(af[1], bfr, acc[1][nf], 0,0,0);
    }
    __syncthreads();
  }
  #pragma unroll
  for (int mf = 0; mf < 2; ++mf){
    #pragma unroll
    for (int nf = 0; nf < 8; ++nf){
      int col = n0 + nf*16 + colg;
      #pragma unroll
      for (int r = 0; r < 4; ++r){
        int row = m0 + w*32 + mf*16 + hi*4 + r;
        float v = acc[mf][nf][r];
        if (RELU) v = v > 0.f ? v : 0.f;
        if (TRANS)      ((float*)Cv)[(size_t)col*ldc + row] = v;
        else if (OUTBF) ((uint16_t*)Cv)[(size_t)row*ldc + col] = f2b(v);
        else            ((float*)Cv)[(size_t)row*ldc + col] = v;
      }
    }
  }
}

// ---------------------------------------------------------------------------
// Fused hypernet layer, v5: 8-phase-style schedule (T3+T4+T5).
// Block: 256 samples x ONE output neuron o. BK=64, dbuf LDS (A 32KB + B
// DINP*128B per buf). 4 phases per K-tile: each phase = {stage chunk of
// tile t+1 || ds_read frag subtile; lgkmcnt(0)+sched_barrier; setprio(1);
// 2mf x NFW MFMAs; setprio(0); barrier}. Tile-boundary wait is counted
// vmcnt(2) (never 0 mid-loop). Chunk-XOR swizzle (row&7) applied on the
// global source (pre-swizzle) and on the ds_read byte offset.
// 8 waves = 4M x 2N (wave 64 x DINP/2). Epilogue: x-contraction as before.
// ---------------------------------------------------------------------------
template<int DINP>
__global__ __launch_bounds__(512, 2) void hyper_layer8(
    const uint16_t* __restrict__ zp,     // [B4, KZ]
    const uint16_t* __restrict__ WpT,    // [128*DINP, KZ]
    const uint16_t* __restrict__ xT,     // [DINP, B4]
    const float*  __restrict__ bsbT,     // [256, B4] transposed: o=b, 128+o=s
    uint16_t* __restrict__ outT,         // [128, B4]
    int relu)
{
  constexpr int NW     = DINP/2;     // wave N-cols
  constexpr int NFW    = DINP/32;    // B frags per kk per wave
  constexpr int BCALLS = DINP/64;    // B stage calls per tile (3 or 2)
  constexpr int ABYTES = 32768;      // A: 256 rows x 128B
  constexpr int BUFSZ  = ABYTES + DINP*128;
  constexpr int NT     = KZ/64;      // 17 K-tiles
  __shared__ char sm[2*BUFSZ];

  int tid = threadIdx.x, w = tid >> 6, lane = tid & 63;
  int wm = w >> 1, wn = w & 1;
  // XCD-aware decode: each XCD owns 2 m-tiles x all 128 neurons
  int f = blockIdx.x;
  int xcd = f & 7;
  int jj = f >> 3;
  int o = jj >> 1;
  int mt = xcd*2 + (jj & 1);
  int m0 = mt*256;
  const uint16_t* Ag = zp  + (size_t)m0*KZ;
  const uint16_t* Bg = WpT + (size_t)o*DINP*KZ;
  int colg = lane & 15, hi = lane >> 4;

  f32x4 acc[4][NFW];
  #pragma unroll
  for (int mf = 0; mf < 4; ++mf)
    #pragma unroll
    for (int nf = 0; nf < NFW; ++nf) acc[mf][nf] = (f32x4){0.f,0.f,0.f,0.f};

  // stage call: 512 threads move 64 rows x 128B (8KB). Linear LDS dest
  // (wave-uniform base + lane*16); source chunk pre-swizzled by row&7.
  auto SA = [&](int t, int c, int a){
    int row = a*64 + (tid >> 3);
    int ch  = (tid & 7) ^ (row & 7);
    gload16(Ag + (size_t)row*KZ + t*64 + ch*8, sm + c*BUFSZ + a*8192 + w*1024);
  };
  auto SB = [&](int t, int c, int b){
    int row = b*64 + (tid >> 3);
    int ch  = (tid & 7) ^ (row & 7);
    gload16(Bg + (size_t)row*KZ + t*64 + ch*8,
            sm + c*BUFSZ + ABYTES + b*8192 + w*1024);
  };
  // frag reads with matching XOR on the 16B-chunk index (cR = kk*4 + hi)
  auto RA = [&](const char* base, int kk, int mf)->bf16x8{
    int row = wm*64 + mf*16 + colg;
    return *(const bf16x8*)(base + row*128 + ((((kk<<2)+hi) ^ (row&7)) << 4));
  };
  auto RB = [&](const char* base, int kk, int nf)->bf16x8{
    int rc = wn*NW + nf*16 + colg;
    return *(const bf16x8*)(base + ABYTES + rc*128 + ((((kk<<2)+hi) ^ (rc&7)) << 4));
  };

  // prologue: stage tile 0 into buf 0
  SA(0,0,0); SA(0,0,1); SA(0,0,2); SA(0,0,3);
  SB(0,0,0); SB(0,0,1);
  if constexpr (BCALLS > 2) SB(0,0,2);

  bf16x8 Bf[NFW], Af0, Af1;
  for (int t = 0; t < NT; ++t){
    int cur = t & 1, nxt = cur ^ 1;
    const char* base = sm + cur*BUFSZ;
    bool pf = (t + 1 < NT);
    // ---- phase 0: boundary wait + B[kk0] + A[kk0, mf 0/1]
    if (pf){
      SA(t+1, nxt, 0); SA(t+1, nxt, 1);
      asm volatile("s_waitcnt vmcnt(2)" ::: "memory");
    } else {
      asm volatile("s_waitcnt vmcnt(0)" ::: "memory");
    }
    __builtin_amdgcn_s_barrier();
    #pragma unroll
    for (int nf = 0; nf < NFW; ++nf) Bf[nf] = RB(base, 0, nf);
    Af0 = RA(base, 0, 0); Af1 = RA(base, 0, 1);
    asm volatile("s_waitcnt lgkmcnt(0)" ::: "memory");
    __builtin_amdgcn_sched_barrier(0);
    __builtin_amdgcn_s_setprio(1);
    #pragma unroll
    for (int nf = 0; nf < NFW; ++nf){
      acc[0][nf] = __builtin_amdgcn_mfma_f32_16x16x32_bf16(Af0, Bf[nf], acc[0][nf], 0,0,0);
      acc[1][nf] = __builtin_amdgcn_mfma_f32_16x16x32_bf16(Af1, Bf[nf], acc[1][nf], 0,0,0);
    }
    __builtin_amdgcn_s_setprio(0);
    __builtin_amdgcn_s_barrier();
    // ---- phase 1: A[kk0, mf 2/3]
    if (pf){ SA(t+1, nxt, 2); SA(t+1, nxt, 3); }
    Af0 = RA(base, 0, 2); Af1 = RA(base, 0, 3);
    asm volatile("s_waitcnt lgkmcnt(0)" ::: "memory");
    __builtin_amdgcn_sched_barrier(0);
    __builtin_amdgcn_s_setprio(1);
    #pragma unroll
    for (int nf = 0; nf < NFW; ++nf){
      acc[2][nf] = __builtin_amdgcn_mfma_f32_16x16x32_bf16(Af0, Bf[nf], acc[2][nf], 0,0,0);
      acc[3][nf] = __builtin_amdgcn_mfma_f32_16x16x32_bf16(Af1, Bf[nf], acc[3][nf], 0,0,0);
    }
    __builtin_amdgcn_s_setprio(0);
    __builtin_amdgcn_s_barrier();
    // ---- phase 2: B[kk1] + A[kk1, mf 0/1]
    if (pf){ SB(t+1, nxt, 0); if constexpr (BCALLS > 1) SB(t+1, nxt, 1); }
    #pragma unroll
    for (int nf = 0; nf < NFW; ++nf) Bf[nf] = RB(base, 1, nf);
    Af0 = RA(base, 1, 0); Af1 = RA(base, 1, 1);
    asm volatile("s_waitcnt lgkmcnt(0)" ::: "memory");
    __builtin_amdgcn_sched_barrier(0);
    __builtin_amdgcn_s_setprio(1);
    #pragma unroll
    for (int nf = 0; nf < NFW; ++nf){
      acc[0][nf] = __builtin_amdgcn_mfma_f32_16x16x32_bf16(Af0, Bf[nf], acc[0][nf], 0,0,0);
      acc[1][nf] = __builtin_amdgcn_mfma_f32_16x16x32_bf16(Af1, Bf[nf], acc[1][nf], 0,0,0);
    }
    __builtin_amdgcn_s_setprio(0);
    __builtin_amdgcn_s_barrier();
    // ---- phase 3: A[kk1, mf 2/3]
    if constexpr (BCALLS > 2) { if (pf) SB(t+1, nxt, 2); }
    Af0 = RA(base, 1, 2); Af1 = RA(base, 1, 3);
    asm volatile("s_waitcnt lgkmcnt(0)" ::: "memory");
    __builtin_amdgcn_sched_barrier(0);
    __builtin_amdgcn_s_setprio(1);
    #pragma unroll
    for (int nf = 0; nf < NFW; ++nf){
      acc[2][nf] = __builtin_amdgcn_mfma_f32_16x16x32_bf16(Af0, Bf[nf], acc[2][nf], 0,0,0);
      acc[3][nf] = __builtin_amdgcn_mfma_f32_16x16x32_bf16(Af1, Bf[nf], acc[3][nf], 0,0,0);
    }
    __builtin_amdgcn_s_setprio(0);
    __builtin_amdgcn_s_barrier();
  }

  // ---- epilogue: contract W rows with x ----
  float pp[4][4];
  #pragma unroll
  for (int mf = 0; mf < 4; ++mf)
    #pragma unroll
    for (int r = 0; r < 4; ++r) pp[mf][r] = 0.f;

  #pragma unroll
  for (int nf = 0; nf < NFW; ++nf){
    int c = wn*NW + nf*16 + colg;
    #pragma unroll
    for (int mf = 0; mf < 4; ++mf){
      int b0 = m0 + wm*64 + mf*16 + hi*4;
      ushort4 xv = *(const ushort4*)(xT + (size_t)c*B4 + b0);
      f32x4 a = acc[mf][nf];
      pp[mf][0] += a[0]*b2f(xv.x); pp[mf][1] += a[1]*b2f(xv.y);
      pp[mf][2] += a[2]*b2f(xv.z); pp[mf][3] += a[3]*b2f(xv.w);
    }
  }
  #pragma unroll
  for (int mf = 0; mf < 4; ++mf)
    #pragma unroll
    for (int off = 1; off < 16; off <<= 1){
      pp[mf][0] += __shfl_xor(pp[mf][0], off);
      pp[mf][1] += __shfl_xor(pp[mf][1], off);
      pp[mf][2] += __shfl_xor(pp[mf][2], off);
      pp[mf][3] += __shfl_xor(pp[mf][3], off);
    }

  // cross-wn reduction via LDS (k-loop done)
  __syncthreads();
  float* red = (float*)sm;    // [2][256]
  if (colg == 0){
    #pragma unroll
    for (int mf = 0; mf < 4; ++mf){
      int rloc = wm*64 + mf*16 + hi*4;
      #pragma unroll
      for (int r = 0; r < 4; ++r) red[wn*256 + rloc + r] = pp[mf][r];
    }
  }
  __syncthreads();
  if (wn == 0 && colg == 0){
    #pragma unroll
    for (int mf = 0; mf < 4; ++mf){
      int rloc = wm*64 + mf*16 + hi*4;
      int b0 = m0 + rloc;
      float4 bv = *(const float4*)(bsbT + (size_t)o*B4 + b0);
      float4 sv = *(const float4*)(bsbT + (size_t)(128+o)*B4 + b0);
      float bb[4] = {bv.x, bv.y, bv.z, bv.w};
      float ss[4] = {sv.x, sv.y, sv.z, sv.w};
      ushort4 st;
      uint16_t* sp = (uint16_t*)&st;
      #pragma unroll
      for (int r = 0; r < 4; ++r){
        float val = (pp[mf][r] + red[256 + rloc + r] + bb[r]) * ss[r];
        if (relu) val = val > 0.f ? val : 0.f;
        sp[r] = f2b(val);
      }
      *(ushort4*)(outT + (size_t)o*B4 + b0) = st;
    }
  }
}

// final layer: out[b,o] = (sum_i w2[b,o*128+i]*x2[i,b] + b2[b,o]) * s2[b,o]
__global__ __launch_bounds__(256) void finalize_k(
    const float* __restrict__ w2, const uint16_t* __restrict__ x2T,
    const float* __restrict__ bs2, float* __restrict__ out)
{
  int tid = threadIdx.x;
  int o = tid & 3;
  int b = blockIdx.x*64 + (tid >> 2);
  const float* wr = w2 + (size_t)b*512 + o*128;
  float dot = 0.f;
  #pragma unroll
  for (int i = 0; i < 128; i += 4){
    float4 wv = *(const float4*)(wr + i);
    dot += wv.x * b2f(x2T[(size_t)(i+0)*B4 + b]);
    dot += wv.y * b2f(x2T[(size_t)(i+1)*B4 + b]);
    dot += wv.z * b2f(x2T[(size_t)(i+2)*B4 + b]);
    dot += wv.w * b2f(x2T[(size_t)(i+3)*B4 + b]);
  }
  float bv = bs2[(size_t)b*128 + o];
  float sv = bs2[(size_t)b*128 + 4 + o];
  out[b*4 + o] = (dot + bv) * sv;
}

// ---------------------------------------------------------------------------
extern "C" void kernel_launch(void* const* d_in, const int* in_sizes, int n_in,
                              void* d_out, int out_size, void* d_ws, size_t ws_size,
                              hipStream_t stream)
{
  const float* obs   = (const float*)d_in[0];
  const float* act   = (const float*)d_in[1];
  const float* prefs = (const float*)d_in[2];
  const float* We1 = (const float*)d_in[3];
  const float* be1 = (const float*)d_in[4];
  const float* We2 = (const float*)d_in[5];
  const float* be2 = (const float*)d_in[6];
  const float* Ww0 = (const float*)d_in[7],  *bw0 = (const float*)d_in[8];
  const float* Wb0 = (const float*)d_in[9],  *bb0 = (const float*)d_in[10];
  const float* Ws0 = (const float*)d_in[11], *bs0i = (const float*)d_in[12];
  const float* Ww1 = (const float*)d_in[13], *bw1 = (const float*)d_in[14];
  const float* Wb1 = (const float*)d_in[15], *bb1 = (const float*)d_in[16];
  const float* Ws1 = (const float*)d_in[17], *bs1i = (const float*)d_in[18];
  const float* Ww2 = (const float*)d_in[19], *bw2 = (const float*)d_in[20];
  const float* Wb2 = (const float*)d_in[21], *bb2 = (const float*)d_in[22];
  const float* Ws2 = (const float*)d_in[23], *bs2i = (const float*)d_in[24];

  char* ws = (char*)d_ws;
  size_t off = 0;
  auto alloc = [&](size_t bytes)->char*{
    char* p = ws + off; off += (bytes + 255) & ~(size_t)255; return p;
  };
  uint16_t* WpT0  = (uint16_t*)alloc((size_t)24576*KZ*2);  // 128 * 192 rows
  uint16_t* WpT1  = (uint16_t*)alloc((size_t)16384*KZ*2);
  uint16_t* WpT2  = (uint16_t*)alloc((size_t)512*KZ*2);
  uint16_t* We1T  = (uint16_t*)alloc((size_t)1024*KH*2);
  uint16_t* We2T  = (uint16_t*)alloc((size_t)1024*KZ*2);
  uint16_t* Wbs0T = (uint16_t*)alloc((size_t)256*KZ*2);    // contiguous with
  uint16_t* Wbs1T = (uint16_t*)alloc((size_t)256*KZ*2);    // Wbs0T (512 rows)
  uint16_t* Wbs2T = (uint16_t*)alloc((size_t)128*KZ*2);
  uint16_t* hinp  = (uint16_t*)alloc((size_t)B4*KH*2);
  uint16_t* z1p   = (uint16_t*)alloc((size_t)B4*KZ*2);
  uint16_t* zp    = (uint16_t*)alloc((size_t)B4*KZ*2);
  float*    bsb0  = (float*)alloc((size_t)256*B4*4);   // transposed [256][B4]
  float*    bsb1  = (float*)alloc((size_t)256*B4*4);   // contiguous with bsb0
  float*    bsb2  = (float*)alloc((size_t)B4*128*4);
  uint16_t* x0T   = (uint16_t*)alloc((size_t)192*B4*2);
  uint16_t* x1T   = (uint16_t*)alloc((size_t)128*B4*2);
  uint16_t* x2T   = (uint16_t*)alloc((size_t)128*B4*2);
  float*    w2    = (float*)alloc((size_t)B4*512*4);
  (void)ws_size; (void)in_sizes; (void)n_in; (void)out_size;

  hipMemsetAsync(Wbs2T, 0, (size_t)128*KZ*2, stream);

  dim3 blk(256);
  auto tg = [](int nc, int kd){ return dim3((nc+31)/32, kd/32); };
  transpose_pack<<<tg(24576,KZ),blk,0,stream>>>(Ww0, bw0, WpT0, 24576, KZ, 1024, 20992, 192, 164);
  transpose_pack<<<tg(16384,KZ),blk,0,stream>>>(Ww1, bw1, WpT1, 16384, KZ, 1024, 16384, 128, 128);
  transpose_pack<<<tg(512,KZ),blk,0,stream>>>(Ww2, bw2, WpT2, 512, KZ, 1024, 512, 128, 128);
  transpose_pack<<<tg(1024,KH),blk,0,stream>>>(We1, be1, We1T, 1024, KH, 132, 1024, 1024, 1024);
  transpose_pack<<<tg(1024,KZ),blk,0,stream>>>(We2, be2, We2T, 1024, KZ, 1024, 1024, 1024, 1024);
  transpose_pack<<<tg(128,KZ),blk,0,stream>>>(Wb0, bb0, Wbs0T,          128, KZ, 1024, 128, 128, 128);
  transpose_pack<<<tg(128,KZ),blk,0,stream>>>(Ws0, bs0i, Wbs0T + 128*KZ,128, KZ, 1024, 128, 128, 128);
  transpose_pack<<<tg(128,KZ),blk,0,stream>>>(Wb1, bb1, Wbs1T,          128, KZ, 1024, 128, 128, 128);
  transpose_pack<<<tg(128,KZ),blk,0,stream>>>(Ws1, bs1i, Wbs1T + 128*KZ,128, KZ, 1024, 128, 128, 128);
  transpose_pack<<<tg(4,KZ),blk,0,stream>>>(Wb2, bb2, Wbs2T,        4, KZ, 1024, 4, 4, 4);
  transpose_pack<<<tg(4,KZ),blk,0,stream>>>(Ws2, bs2i, Wbs2T + 4*KZ,4, KZ, 1024, 4, 4, 4);

  pack_hin<<<dim3(B4*KH/256),blk,0,stream>>>(obs, prefs, hinp);
  pack_x0T<<<dim3(192*B4/256),blk,0,stream>>>(obs, act, prefs, x0T);
  zinit<<<dim3(B4*128/256),blk,0,stream>>>(z1p, zp);

  // z1 = relu(hin' @ We1')   [B,1024] bf16 into z1p (stride KZ)
  gemm128<1,1,0><<<dim3(32,8),blk,0,stream>>>(hinp, KH, We1T, KH, z1p, KZ, KH);
  // z = relu(z1' @ We2')     [B,1024] bf16 into zp (stride KZ)
  gemm128<1,1,0><<<dim3(32,8),blk,0,stream>>>(z1p, KZ, We2T, KZ, zp, KZ, KZ);
  // bias/scale heads for layers 0+1 in ONE launch (Wbs0T/Wbs1T contiguous,
  // bsb0/bsb1 contiguous): fp32 TRANSPOSED [512][B4]
  gemm128<0,0,1><<<dim3(32,4),blk,0,stream>>>(zp, KZ, Wbs0T, KZ, bsb0, B4, KZ);
  gemm128<0,0,0><<<dim3(32,1),blk,0,stream>>>(zp, KZ, Wbs2T, KZ, bsb2, 128, KZ);

  // fused hyper layers 0 and 1 (XCD-swizzled 1D grid: 8 xcd * 128 o * 2 m)
  hyper_layer8<192><<<dim3(2048),dim3(512),0,stream>>>(zp, WpT0, x0T, bsb0, x1T, 1);
  hyper_layer8<128><<<dim3(2048),dim3(512),0,stream>>>(zp, WpT1, x1T, bsb1, x2T, 1);

  // layer 2: materialize small w2 then finalize
  gemm128<0,0,0><<<dim3(32,4),blk,0,stream>>>(zp, KZ, WpT2, KZ, w2, 512, KZ);
  finalize_k<<<dim3(B4/64),blk,0,stream>>>(w2, x2T, bsb2, (float*)d_out);
}

// Round 6
// 633.683 us; speedup vs baseline: 2.4877x; 1.0460x over previous
//
#include <hip/hip_runtime.h>
#include <hip/hip_bf16.h>
#include <stdint.h>

#define B4 4096
#define KZ 1088   // padded z width: 1024 + 1 (ones col for bias) + 63 zero pad (34 x 32)
#define KH 160    // padded hypernet-input width: 132 + 1 + pad

typedef short bf16x8 __attribute__((ext_vector_type(8)));
typedef float f32x4 __attribute__((ext_vector_type(4)));

__device__ __forceinline__ float b2f(uint16_t u){
  union {float f; uint32_t i;} v; v.i = ((uint32_t)u)<<16; return v.f;
}
__device__ __forceinline__ uint16_t f2b(float f){
  union {float fv; uint32_t i;} v; v.fv = f;
  uint32_t r = v.i + 0x7FFFu + ((v.i>>16)&1u);
  return (uint16_t)(r>>16);
}
__device__ __forceinline__ void gload16(const void* g, void* l){
  __builtin_amdgcn_global_load_lds(
      (__attribute__((address_space(1))) void*)(g),
      (__attribute__((address_space(3))) void*)(l), 16, 0, 0);
}

// ---------------------------------------------------------------------------
// Transpose+pack: dst[c][k] (bf16, K-contiguous) from src fp32 [Ksrc][src_ld].
// Row k==Ksrc gets bias[sc]; k>Ksrc gets 0. Column map handles din padding:
// o=c/din_dst, i=c%din_dst, valid iff i<din_src.
// ---------------------------------------------------------------------------
__global__ __launch_bounds__(256) void transpose_pack(
    const float* __restrict__ src, const float* __restrict__ bias,
    uint16_t* __restrict__ dst,
    int Ncols, int Kdst, int Ksrc, int src_ld, int din_dst, int din_src)
{
  __shared__ float tile[32][33];
  int ct = blockIdx.x, kt = blockIdx.y;
  int tid = threadIdx.x;
  int cl = tid & 31, kg = tid >> 5;
  #pragma unroll
  for (int r = 0; r < 4; ++r){
    int kl = kg*4 + r;
    int k  = kt*32 + kl;
    int c  = ct*32 + cl;
    float v = 0.f;
    if (c < Ncols){
      int o = c / din_dst, i = c - o*din_dst;
      if (i < din_src){
        int sc = o*din_src + i;
        if (k < Ksrc)       v = src[(size_t)k*src_ld + sc];
        else if (k == Ksrc) v = bias[sc];
      }
    }
    tile[kl][cl] = v;
  }
  __syncthreads();
  #pragma unroll
  for (int r = 0; r < 4; ++r){
    int cl2 = kg*4 + r;
    int c = ct*32 + cl2;
    int k = kt*32 + (tid & 31);
    if (c < Ncols) dst[(size_t)c*Kdst + k] = f2b(tile[tid & 31][cl2]);
  }
}

// hinp[b][k] bf16: [obs | prefs | 1 | 0...], width KH
__global__ __launch_bounds__(256) void pack_hin(
    const float* __restrict__ obs, const float* __restrict__ prefs,
    uint16_t* __restrict__ hinp)
{
  int idx = blockIdx.x*256 + threadIdx.x;   // over B4*KH
  int b = idx / KH, k = idx - b*KH;
  float v;
  if (k < 128)      v = obs[b*128 + k];
  else if (k < 132) v = prefs[b*4 + (k-128)];
  else              v = (k == 132) ? 1.f : 0.f;
  hinp[idx] = f2b(v);
}

// x0T[c][b] bf16 transposed: c<128 obs, c<160 action, c<164 prefs, else 0.
// 192 rows (din padded to 192).
__global__ __launch_bounds__(256) void pack_x0T(
    const float* __restrict__ obs, const float* __restrict__ act,
    const float* __restrict__ prefs, uint16_t* __restrict__ x0T)
{
  int idx = blockIdx.x*256 + threadIdx.x;   // over 192*B4
  int c = idx >> 12;
  int b = idx & (B4-1);
  float v = 0.f;
  if (c < 128)      v = obs[b*128 + c];
  else if (c < 160) v = act[b*32 + (c-128)];
  else if (c < 164) v = prefs[b*4 + (c-160)];
  x0T[idx] = f2b(v);
}

// set cols 1024..1087 of z1p and zp: 1.0 at 1024, zeros after
__global__ __launch_bounds__(256) void zinit(uint16_t* __restrict__ z1p,
                                             uint16_t* __restrict__ zp)
{
  int idx = blockIdx.x*256 + threadIdx.x;   // over B4*128
  int t = idx & 127;
  int row = idx >> 7;
  uint16_t* p = (t < 64) ? z1p : zp;
  int col = 1024 + (t & 63);
  p[(size_t)row*KZ + col] = ((t & 63) == 0) ? (uint16_t)0x3F80 : (uint16_t)0;
}

// ---------------------------------------------------------------------------
// Generic 128x128 MFMA GEMM: C[M,N] = act(A[M,K] @ BT[N,K]^T)
// A, BT bf16 (K-contiguous rows), C fp32 or bf16. 4 waves, wave = 32-row slab.
// TRANS=1: store fp32 transposed C^T[col*ldc + row] (for bias/scale buffers).
// ---------------------------------------------------------------------------
template<int RELU, int OUTBF, int TRANS>
__global__ __launch_bounds__(256) void gemm128(
    const uint16_t* __restrict__ A, int lda,
    const uint16_t* __restrict__ BT, int ldb,
    void* __restrict__ Cv, int ldc, int K)
{
  __shared__ char smA[128*64];
  __shared__ char smB[128*64];
  int tid = threadIdx.x, w = tid >> 6, lane = tid & 63;
  int m0 = blockIdx.x*128, n0 = blockIdx.y*128;
  const uint16_t* Ab = A  + (size_t)m0*lda;
  const uint16_t* Bb = BT + (size_t)n0*ldb;
  f32x4 acc[2][8];
  #pragma unroll
  for (int mf = 0; mf < 2; ++mf)
    #pragma unroll
    for (int nf = 0; nf < 8; ++nf) acc[mf][nf] = (f32x4){0.f,0.f,0.f,0.f};
  int colg = lane & 15, hi = lane >> 4;

  for (int k0 = 0; k0 < K; k0 += 32){
    #pragma unroll
    for (int p = 0; p < 2; ++p){
      int rb = p*4 + w;
      int row = rb*16 + (lane >> 2);
      int chunk = (lane & 3) ^ ((row >> 1) & 3);
      gload16(Ab + (size_t)row*lda + k0 + chunk*8, &smA[rb*1024]);
      gload16(Bb + (size_t)row*ldb + k0 + chunk*8, &smB[rb*1024]);
    }
    __syncthreads();
    bf16x8 af[2];
    #pragma unroll
    for (int mf = 0; mf < 2; ++mf){
      int row = w*32 + mf*16 + colg;
      af[mf] = *(const bf16x8*)&smA[row*64 + ((hi ^ ((row>>1)&3)) << 4)];
    }
    #pragma unroll
    for (int nf = 0; nf < 8; ++nf){
      int row = nf*16 + colg;
      bf16x8 bfr = *(const bf16x8*)&smB[row*64 + ((hi ^ ((row>>1)&3)) << 4)];
      acc[0][nf] = __builtin_amdgcn_mfma_f32_16x16x32_bf16(af[0], bfr, acc[0][nf], 0,0,0);
      acc[1][nf] = __builtin_amdgcn_mfma_f32_16x16x32_bf16(af[1], bfr, acc[1][nf], 0,0,0);
    }
    __syncthreads();
  }
  #pragma unroll
  for (int mf = 0; mf < 2; ++mf){
    #pragma unroll
    for (int nf = 0; nf < 8; ++nf){
      int col = n0 + nf*16 + colg;
      #pragma unroll
      for (int r = 0; r < 4; ++r){
        int row = m0 + w*32 + mf*16 + hi*4 + r;
        float v = acc[mf][nf][r];
        if (RELU) v = v > 0.f ? v : 0.f;
        if (TRANS)      ((float*)Cv)[(size_t)col*ldc + row] = v;
        else if (OUTBF) ((uint16_t*)Cv)[(size_t)row*ldc + col] = f2b(v);
        else            ((float*)Cv)[(size_t)row*ldc + col] = v;
      }
    }
  }
}

// ---------------------------------------------------------------------------
// Fused hypernet layer v6 (m201-geometry): block = 256 samples x TWO neurons
// (BN = 2*DINP). 8 waves 2M x 4N, wave tile 128 x DINP/2 (mf=8, nf=DINP/32).
// K pipeline: 34 half-tiles of K=32, THREE LDS half-buffers, prefetch
// distance 2, ONE barrier + counted vmcnt per half (never 0 mid-loop).
// 2 phases per half: {read B[NF]+A[0..3], issue SA(h+2); lgkm; 4xNF MFMA},
// {read A[4..7], issue SB(h+2); lgkm; 4xNF MFMA}. Chunk-XOR swizzle
// ((row>>1)&3) pre-applied on global source, matched on ds_read (rule 21).
// Epilogue: x-contraction, colg shuffle-reduce, cross-wn LDS reduce per
// neuron, bias+scale(+relu), store outT[o][b].
// ---------------------------------------------------------------------------
template<int DINP>
__global__ __launch_bounds__(512, 2) void hyper2n(
    const uint16_t* __restrict__ zp,     // [B4, KZ]
    const uint16_t* __restrict__ WpT,    // [128*DINP, KZ] grouped by neuron
    const uint16_t* __restrict__ xT,     // [DINP, B4]
    const float*  __restrict__ bsbT,     // [256, B4]: row o=bias, 128+o=scale
    uint16_t* __restrict__ outT,         // [128, B4]
    int relu)
{
  constexpr int NF     = DINP/32;        // frags per wave per k-half (6 / 4)
  constexpr int BCALLS = DINP/64;        // B stage calls per half (3 / 2)
  constexpr int WAITN  = 2 + BCALLS;     // counted vmcnt at half boundary
  constexpr int HBUF   = 16384 + 2*DINP*64;  // A 16KB + B 2*DINP rows x 64B
  constexpr int NH     = KZ/32;          // 34 half-tiles
  __shared__ char sm[3*HBUF];

  int tid = threadIdx.x, w = tid >> 6, lane = tid & 63;
  int wm = w >> 2, wn = w & 3;           // 2M x 4N
  // XCD decode: 1024 blocks; each XCD owns 2 m-tiles x all 64 neuron-pairs
  int f = blockIdx.x;
  int xcd = f & 7;
  int j = f >> 3;               // 0..127
  int pair = j >> 1;            // 0..63
  int mt = xcd*2 + (j & 1);     // 0..15
  int m0 = mt*256;
  const uint16_t* Ag = zp  + (size_t)m0*KZ;
  const uint16_t* Bg = WpT + (size_t)pair*(2*DINP)*KZ;
  int colg = lane & 15, hi = lane >> 4;

  f32x4 acc[8][NF];
  #pragma unroll
  for (int mf = 0; mf < 8; ++mf)
    #pragma unroll
    for (int nf = 0; nf < NF; ++nf) acc[mf][nf] = (f32x4){0.f,0.f,0.f,0.f};

  // stage call: 512 threads x 16B = 8KB = 128 rows x 64B. Linear LDS dest
  // (wave-uniform base + lane*16); 16B-chunk pre-swizzled by (row>>1)&3.
  auto SA = [&](int h, int a){
    int row = a*128 + (tid >> 2);
    int ch  = (tid & 3) ^ ((row >> 1) & 3);
    gload16(Ag + (size_t)row*KZ + h*32 + ch*8,
            sm + (h%3)*HBUF + a*8192 + w*1024);
  };
  auto SB = [&](int h, int b){
    int row = b*128 + (tid >> 2);
    int ch  = (tid & 3) ^ ((row >> 1) & 3);
    gload16(Bg + (size_t)row*KZ + h*32 + ch*8,
            sm + (h%3)*HBUF + 16384 + b*8192 + w*1024);
  };

  // prologue: stage halves 0 and 1
  SA(0,0); SA(0,1);
  #pragma unroll
  for (int b = 0; b < BCALLS; ++b) SB(0,b);
  SA(1,0); SA(1,1);
  #pragma unroll
  for (int b = 0; b < BCALLS; ++b) SB(1,b);

  for (int h = 0; h < NH; ++h){
    const char* base = sm + (h%3)*HBUF;
    if (h == NH-1) asm volatile("s_waitcnt vmcnt(0)" ::: "memory");
    else           asm volatile("s_waitcnt vmcnt(%0)" :: "i"(WAITN) : "memory");
    __builtin_amdgcn_s_barrier();
    // ---- phase 0: B[all nf] + A[mf 0..3]
    bf16x8 Bf[NF];
    #pragma unroll
    for (int nf = 0; nf < NF; ++nf){
      int rc = wn*(DINP/2) + nf*16 + colg;
      Bf[nf] = *(const bf16x8*)(base + 16384 + rc*64 + ((hi ^ ((rc>>1)&3)) << 4));
    }
    bf16x8 Af[4];
    #pragma unroll
    for (int m = 0; m < 4; ++m){
      int row = wm*128 + m*16 + colg;
      Af[m] = *(const bf16x8*)(base + row*64 + ((hi ^ ((row>>1)&3)) << 4));
    }
    if (h + 2 < NH){ SA(h+2,0); SA(h+2,1); }
    asm volatile("s_waitcnt lgkmcnt(0)" ::: "memory");
    __builtin_amdgcn_sched_barrier(0);
    __builtin_amdgcn_s_setprio(1);
    #pragma unroll
    for (int nf = 0; nf < NF; ++nf)
      #pragma unroll
      for (int m = 0; m < 4; ++m)
        acc[m][nf] = __builtin_amdgcn_mfma_f32_16x16x32_bf16(Af[m], Bf[nf], acc[m][nf], 0,0,0);
    __builtin_amdgcn_s_setprio(0);
    // ---- phase 1: A[mf 4..7]
    #pragma unroll
    for (int m = 0; m < 4; ++m){
      int row = wm*128 + (4+m)*16 + colg;
      Af[m] = *(const bf16x8*)(base + row*64 + ((hi ^ ((row>>1)&3)) << 4));
    }
    if (h + 2 < NH){
      #pragma unroll
      for (int b = 0; b < BCALLS; ++b) SB(h+2,b);
    }
    asm volatile("s_waitcnt lgkmcnt(0)" ::: "memory");
    __builtin_amdgcn_sched_barrier(0);
    __builtin_amdgcn_s_setprio(1);
    #pragma unroll
    for (int nf = 0; nf < NF; ++nf)
      #pragma unroll
      for (int m = 0; m < 4; ++m)
        acc[4+m][nf] = __builtin_amdgcn_mfma_f32_16x16x32_bf16(Af[m], Bf[nf], acc[4+m][nf], 0,0,0);
    __builtin_amdgcn_s_setprio(0);
  }

  // ---- epilogue: contract W rows with x ----
  float pp[8][4];
  #pragma unroll
  for (int mf = 0; mf < 8; ++mf)
    #pragma unroll
    for (int r = 0; r < 4; ++r) pp[mf][r] = 0.f;

  #pragma unroll
  for (int nf = 0; nf < NF; ++nf){
    int il = (wn & 1)*(DINP/2) + nf*16 + colg;   // din-local index
    #pragma unroll
    for (int mf = 0; mf < 8; ++mf){
      int b0 = m0 + wm*128 + mf*16 + hi*4;
      ushort4 xv = *(const ushort4*)(xT + (size_t)il*B4 + b0);
      f32x4 a = acc[mf][nf];
      pp[mf][0] += a[0]*b2f(xv.x); pp[mf][1] += a[1]*b2f(xv.y);
      pp[mf][2] += a[2]*b2f(xv.z); pp[mf][3] += a[3]*b2f(xv.w);
    }
  }
  #pragma unroll
  for (int mf = 0; mf < 8; ++mf)
    #pragma unroll
    for (int off = 1; off < 16; off <<= 1){
      pp[mf][0] += __shfl_xor(pp[mf][0], off);
      pp[mf][1] += __shfl_xor(pp[mf][1], off);
      pp[mf][2] += __shfl_xor(pp[mf][2], off);
      pp[mf][3] += __shfl_xor(pp[mf][3], off);
    }

  // cross-wn reduce per neuron: waves (wn&1)==1 write, (wn&1)==0 finish
  __syncthreads();
  float* red = (float*)sm;    // [2 o_local][256 rows]
  if (colg == 0 && (wn & 1) == 1){
    #pragma unroll
    for (int mf = 0; mf < 8; ++mf){
      int rloc = wm*128 + mf*16 + hi*4;
      #pragma unroll
      for (int r = 0; r < 4; ++r) red[(wn>>1)*256 + rloc + r] = pp[mf][r];
    }
  }
  __syncthreads();
  if (colg == 0 && (wn & 1) == 0){
    int o = pair*2 + (wn >> 1);
    #pragma unroll
    for (int mf = 0; mf < 8; ++mf){
      int rloc = wm*128 + mf*16 + hi*4;
      int b0 = m0 + rloc;
      float4 bv = *(const float4*)(bsbT + (size_t)o*B4 + b0);
      float4 sv = *(const float4*)(bsbT + (size_t)(128+o)*B4 + b0);
      float bb[4] = {bv.x, bv.y, bv.z, bv.w};
      float ss[4] = {sv.x, sv.y, sv.z, sv.w};
      ushort4 st;
      uint16_t* sp = (uint16_t*)&st;
      #pragma unroll
      for (int r = 0; r < 4; ++r){
        float val = (pp[mf][r] + red[(wn>>1)*256 + rloc + r] + bb[r]) * ss[r];
        if (relu) val = val > 0.f ? val : 0.f;
        sp[r] = f2b(val);
      }
      *(ushort4*)(outT + (size_t)o*B4 + b0) = st;
    }
  }
}

// final layer: out[b,o] = (sum_i w2[b,o*128+i]*x2[i,b] + b2[b,o]) * s2[b,o]
__global__ __launch_bounds__(256) void finalize_k(
    const float* __restrict__ w2, const uint16_t* __restrict__ x2T,
    const float* __restrict__ bs2, float* __restrict__ out)
{
  int tid = threadIdx.x;
  int o = tid & 3;
  int b = blockIdx.x*64 + (tid >> 2);
  const float* wr = w2 + (size_t)b*512 + o*128;
  float dot = 0.f;
  #pragma unroll
  for (int i = 0; i < 128; i += 4){
    float4 wv = *(const float4*)(wr + i);
    dot += wv.x * b2f(x2T[(size_t)(i+0)*B4 + b]);
    dot += wv.y * b2f(x2T[(size_t)(i+1)*B4 + b]);
    dot += wv.z * b2f(x2T[(size_t)(i+2)*B4 + b]);
    dot += wv.w * b2f(x2T[(size_t)(i+3)*B4 + b]);
  }
  float bv = bs2[(size_t)b*128 + o];
  float sv = bs2[(size_t)b*128 + 4 + o];
  out[b*4 + o] = (dot + bv) * sv;
}

// ---------------------------------------------------------------------------
extern "C" void kernel_launch(void* const* d_in, const int* in_sizes, int n_in,
                              void* d_out, int out_size, void* d_ws, size_t ws_size,
                              hipStream_t stream)
{
  const float* obs   = (const float*)d_in[0];
  const float* act   = (const float*)d_in[1];
  const float* prefs = (const float*)d_in[2];
  const float* We1 = (const float*)d_in[3];
  const float* be1 = (const float*)d_in[4];
  const float* We2 = (const float*)d_in[5];
  const float* be2 = (const float*)d_in[6];
  const float* Ww0 = (const float*)d_in[7],  *bw0 = (const float*)d_in[8];
  const float* Wb0 = (const float*)d_in[9],  *bb0 = (const float*)d_in[10];
  const float* Ws0 = (const float*)d_in[11], *bs0i = (const float*)d_in[12];
  const float* Ww1 = (const float*)d_in[13], *bw1 = (const float*)d_in[14];
  const float* Wb1 = (const float*)d_in[15], *bb1 = (const float*)d_in[16];
  const float* Ws1 = (const float*)d_in[17], *bs1i = (const float*)d_in[18];
  const float* Ww2 = (const float*)d_in[19], *bw2 = (const float*)d_in[20];
  const float* Wb2 = (const float*)d_in[21], *bb2 = (const float*)d_in[22];
  const float* Ws2 = (const float*)d_in[23], *bs2i = (const float*)d_in[24];

  char* ws = (char*)d_ws;
  size_t off = 0;
  auto alloc = [&](size_t bytes)->char*{
    char* p = ws + off; off += (bytes + 255) & ~(size_t)255; return p;
  };
  uint16_t* WpT0  = (uint16_t*)alloc((size_t)24576*KZ*2);  // 128 * 192 rows
  uint16_t* WpT1  = (uint16_t*)alloc((size_t)16384*KZ*2);
  uint16_t* WpT2  = (uint16_t*)alloc((size_t)512*KZ*2);
  uint16_t* We1T  = (uint16_t*)alloc((size_t)1024*KH*2);
  uint16_t* We2T  = (uint16_t*)alloc((size_t)1024*KZ*2);
  uint16_t* Wbs0T = (uint16_t*)alloc((size_t)256*KZ*2);    // contiguous with
  uint16_t* Wbs1T = (uint16_t*)alloc((size_t)256*KZ*2);    // Wbs0T (512 rows)
  uint16_t* Wbs2T = (uint16_t*)alloc((size_t)128*KZ*2);
  uint16_t* hinp  = (uint16_t*)alloc((size_t)B4*KH*2);
  uint16_t* z1p   = (uint16_t*)alloc((size_t)B4*KZ*2);
  uint16_t* zp    = (uint16_t*)alloc((size_t)B4*KZ*2);
  float*    bsb0  = (float*)alloc((size_t)256*B4*4);   // transposed [256][B4]
  float*    bsb1  = (float*)alloc((size_t)256*B4*4);   // contiguous with bsb0
  float*    bsb2  = (float*)alloc((size_t)B4*128*4);
  uint16_t* x0T   = (uint16_t*)alloc((size_t)192*B4*2);
  uint16_t* x1T   = (uint16_t*)alloc((size_t)128*B4*2);
  uint16_t* x2T   = (uint16_t*)alloc((size_t)128*B4*2);
  float*    w2    = (float*)alloc((size_t)B4*512*4);
  (void)ws_size; (void)in_sizes; (void)n_in; (void)out_size;

  hipMemsetAsync(Wbs2T, 0, (size_t)128*KZ*2, stream);

  dim3 blk(256);
  auto tg = [](int nc, int kd){ return dim3((nc+31)/32, kd/32); };
  transpose_pack<<<tg(24576,KZ),blk,0,stream>>>(Ww0, bw0, WpT0, 24576, KZ, 1024, 20992, 192, 164);
  transpose_pack<<<tg(16384,KZ),blk,0,stream>>>(Ww1, bw1, WpT1, 16384, KZ, 1024, 16384, 128, 128);
  transpose_pack<<<tg(512,KZ),blk,0,stream>>>(Ww2, bw2, WpT2, 512, KZ, 1024, 512, 128, 128);
  transpose_pack<<<tg(1024,KH),blk,0,stream>>>(We1, be1, We1T, 1024, KH, 132, 1024, 1024, 1024);
  transpose_pack<<<tg(1024,KZ),blk,0,stream>>>(We2, be2, We2T, 1024, KZ, 1024, 1024, 1024, 1024);
  transpose_pack<<<tg(128,KZ),blk,0,stream>>>(Wb0, bb0, Wbs0T,          128, KZ, 1024, 128, 128, 128);
  transpose_pack<<<tg(128,KZ),blk,0,stream>>>(Ws0, bs0i, Wbs0T + 128*KZ,128, KZ, 1024, 128, 128, 128);
  transpose_pack<<<tg(128,KZ),blk,0,stream>>>(Wb1, bb1, Wbs1T,          128, KZ, 1024, 128, 128, 128);
  transpose_pack<<<tg(128,KZ),blk,0,stream>>>(Ws1, bs1i, Wbs1T + 128*KZ,128, KZ, 1024, 128, 128, 128);
  transpose_pack<<<tg(4,KZ),blk,0,stream>>>(Wb2, bb2, Wbs2T,        4, KZ, 1024, 4, 4, 4);
  transpose_pack<<<tg(4,KZ),blk,0,stream>>>(Ws2, bs2i, Wbs2T + 4*KZ,4, KZ, 1024, 4, 4, 4);

  pack_hin<<<dim3(B4*KH/256),blk,0,stream>>>(obs, prefs, hinp);
  pack_x0T<<<dim3(192*B4/256),blk,0,stream>>>(obs, act, prefs, x0T);
  zinit<<<dim3(B4*128/256),blk,0,stream>>>(z1p, zp);

  // z1 = relu(hin' @ We1')   [B,1024] bf16 into z1p (stride KZ)
  gemm128<1,1,0><<<dim3(32,8),blk,0,stream>>>(hinp, KH, We1T, KH, z1p, KZ, KH);
  // z = relu(z1' @ We2')     [B,1024] bf16 into zp (stride KZ)
  gemm128<1,1,0><<<dim3(32,8),blk,0,stream>>>(z1p, KZ, We2T, KZ, zp, KZ, KZ);
  // bias/scale heads for layers 0+1 in ONE launch: fp32 TRANSPOSED [512][B4]
  gemm128<0,0,1><<<dim3(32,4),blk,0,stream>>>(zp, KZ, Wbs0T, KZ, bsb0, B4, KZ);
  gemm128<0,0,0><<<dim3(32,1),blk,0,stream>>>(zp, KZ, Wbs2T, KZ, bsb2, 128, KZ);

  // fused hyper layers 0 and 1: 1024 blocks (8 xcd * 64 pairs * 2 m-tiles)
  hyper2n<192><<<dim3(1024),dim3(512),0,stream>>>(zp, WpT0, x0T, bsb0, x1T, 1);
  hyper2n<128><<<dim3(1024),dim3(512),0,stream>>>(zp, WpT1, x1T, bsb1, x2T, 1);

  // layer 2: materialize small w2 then finalize
  gemm128<0,0,0><<<dim3(32,4),blk,0,stream>>>(zp, KZ, WpT2, KZ, w2, 512, KZ);
  finalize_k<<<dim3(B4/64),blk,0,stream>>>(w2, x2T, bsb2, (float*)d_out);
}